// Round 6
// baseline (492.775 us; speedup 1.0000x reference)
//
#include <hip/hip_runtime.h>
#include <hip/hip_bf16.h>
#include <stdint.h>

typedef __bf16 bf16;
typedef bf16 bf16x8 __attribute__((ext_vector_type(8)));
typedef bf16 bf16x4 __attribute__((ext_vector_type(4)));
typedef float f32x4 __attribute__((ext_vector_type(4)));

#define NQ_    8
#define EMBED_ 1024
#define FFN_   4096
#define MROWS  32768   // B*S = 8*4096
#define NOUT   1024    // EMBED
#define NT_    (FFN_ / 64)   // 64 K-tiles of BK=64

// ---- async global->LDS, 16B per lane, wave-uniform LDS base ----
__device__ __forceinline__ void gl_lds16(const bf16* g, bf16* l) {
  __builtin_amdgcn_global_load_lds(
      (__attribute__((address_space(1))) void*)(const_cast<bf16*>(g)),
      (__attribute__((address_space(3))) void*)l, 16, 0, 0);
}

#define BAR()   __builtin_amdgcn_s_barrier()
#define VM2()   asm volatile("s_waitcnt vmcnt(2)" ::: "memory")
#define VM0()   asm volatile("s_waitcnt vmcnt(0)" ::: "memory")
#define MFMA(a, b, c) __builtin_amdgcn_mfma_f32_16x16x32_bf16((a), (b), (c), 0, 0, 0)

// ============================================================
// Kernel 1: W_out f32 -> bf16
// ============================================================
__global__ __launch_bounds__(256) void k_wcvt(const float* __restrict__ w,
                                              bf16* __restrict__ wb) {
  const int i = (blockIdx.x * 256 + threadIdx.x) * 4;
  const float4 v = *(const float4*)(w + i);
  bf16x4 o;
  o[0] = (bf16)v.x; o[1] = (bf16)v.y; o[2] = (bf16)v.z; o[3] = (bf16)v.w;
  *(bf16x4*)(wb + i) = o;
}

// ============================================================
// Kernel 2: theta = x @ W_enc^T ; z = analytic circuit expvals
//   z_0 = prod_{w=1..7} cos(theta_w); z_k = prod_{w=0..k} cos(theta_w)
// ============================================================
__global__ __launch_bounds__(256) void k_encode(const float* __restrict__ x,
                                                const float* __restrict__ Wenc,
                                                float* __restrict__ z) {
  const int t = threadIdx.x;
  const int wave = t >> 6, lane = t & 63;
  const int r0 = blockIdx.x * 16;

  float4 we[8];
#pragma unroll
  for (int q = 0; q < 8; ++q)
    we[q] = *(const float4*)(Wenc + q * EMBED_ + t * 4);

  __shared__ float red[16][4][8];
  __shared__ float cb[16][8];

  for (int rr = 0; rr < 16; ++rr) {
    const float4 xv = *(const float4*)(x + (size_t)(r0 + rr) * EMBED_ + t * 4);
#pragma unroll
    for (int q = 0; q < 8; ++q) {
      float v = xv.x * we[q].x + xv.y * we[q].y + xv.z * we[q].z + xv.w * we[q].w;
#pragma unroll
      for (int off = 32; off > 0; off >>= 1) v += __shfl_xor(v, off, 64);
      if (lane == 0) red[rr][wave][q] = v;
    }
  }
  __syncthreads();
  if (t < 128) {
    const int rr = t >> 3, q = t & 7;
    const float th = red[rr][0][q] + red[rr][1][q] + red[rr][2][q] + red[rr][3][q];
    cb[rr][q] = cosf(th);
  }
  __syncthreads();
  if (t < 16) {
    float c[8];
#pragma unroll
    for (int q = 0; q < 8; ++q) c[q] = cb[t][q];
    float zz[8];
    zz[0] = c[1] * c[2] * c[3] * c[4] * c[5] * c[6] * c[7];
    float p = c[0];
#pragma unroll
    for (int k = 1; k < 8; ++k) { p *= c[k]; zz[k] = p; }
    float4* zp = (float4*)(z + (size_t)(r0 + t) * 8);
    zp[0] = make_float4(zz[0], zz[1], zz[2], zz[3]);
    zp[1] = make_float4(zz[4], zz[5], zz[6], zz[7]);
  }
}

// ============================================================
// Kernel 3: h = relu(z @ W_dec^T) -> bf16 [chunk_rows][4096]
// ============================================================
__global__ __launch_bounds__(256) void k_hgen(const float* __restrict__ z,
                                              const float* __restrict__ Wdec,
                                              bf16* __restrict__ h,
                                              int row0) {
  const int t = threadIdx.x;
  const int f0 = blockIdx.y * 2048 + t * 8;
  const int g0 = row0 + blockIdx.x * 64;
  const int l0 = blockIdx.x * 64;

  float4 wd[16];
#pragma unroll
  for (int i = 0; i < 16; ++i)
    wd[i] = *(const float4*)(Wdec + (size_t)f0 * 8 + i * 4);

  for (int rr = 0; rr < 64; ++rr) {
    const float4* zp = (const float4*)(z + (size_t)(g0 + rr) * 8);
    const float4 z0 = zp[0], z1 = zp[1];
    bf16x8 o;
#pragma unroll
    for (int j = 0; j < 8; ++j) {
      const float4 a = wd[j * 2], b = wd[j * 2 + 1];
      float s = a.x * z0.x + a.y * z0.y + a.z * z0.z + a.w * z0.w +
                b.x * z1.x + b.y * z1.y + b.z * z1.z + b.w * z1.w;
      o[j] = (bf16)fmaxf(s, 0.0f);
    }
    *(bf16x8*)(h + (size_t)(l0 + rr) * FFN_ + f0) = o;
  }
}

// ============================================================
// Kernel 4: out = h @ W_out^T — 256x256xBK64 8-phase schedule
// T1 XCD-swizzle + T2 3-bit slot swizzle (conflicts==0 @ r5) +
// T3/T4 counted vmcnt + T5 setprio + QUADRANT REGISTER PREFETCH:
// each quadrant's ds_reads issue one phase early; no explicit lgkmcnt(0)
// drains — the compiler's dependency-tracked counted lgkmcnt lets pending
// reads complete UNDER the previous quadrant's MFMA (r5: serial reads
// were ~half the 53% non-MFMA time).
// Stage ledger unchanged (forced): s1,s2,s3(T+1)@ph1-3 -> buf c̄,
// s0(T+2)@ph4 -> buf c (safe: all buf-c reads issued by ph2, retired
// well before the staged data can land); VM2 leaves s0(T+2) in flight.
// ============================================================
__global__ __launch_bounds__(512, 2) void k_gemm8(const bf16* __restrict__ A,
                                                  const bf16* __restrict__ Bt,
                                                  float* __restrict__ C,
                                                  int row0) {
  __shared__ bf16 lds[65536];  // 128 KiB: buf c at c*32768 elems = [A 16384 | B 16384]

  // bijective XCD swizzle (m204)
  const int nwg = (int)gridDim.x, orig = (int)blockIdx.x;
  const int qd = nwg >> 3, rm = nwg & 7;
  const int xcd = orig & 7;
  const int bid = (xcd < rm ? xcd * (qd + 1) : rm * (qd + 1) + (xcd - rm) * qd) + (orig >> 3);
  const int mi = bid >> 2, ni = bid & 3;

  const int t = threadIdx.x;
  const int wave = t >> 6, lane = t & 63;
  const int wm = wave >> 2, wn = wave & 3;

  // staging geometry: chunk q = i*512 + t ; row = q>>3 ; slot = q&7
  // source pre-swizzle: fetch global slot (q&7) ^ (row&7) into linear LDS slot
  const int qrow0 = t >> 3;
  const int qc8 = (t & 7) ^ ((t >> 3) & 7);
  const size_t Abase = (size_t)(mi * 256) * FFN_;
  const size_t Bbase = (size_t)(ni * 256) * FFN_;
  const int wbase = wave * 512;                // wave-uniform LDS base (1024 B/wave)

  const int fr = lane & 15, fk = (lane >> 4) * 8;

  f32x4 acc[8][4] = {};

  auto stage = [&](int s, int T1) {            // s: 0=A rows 0-127, 1=A 128-255, 2=B 0-127, 3=B 128-255
    const int c = T1 & 1;
    const bf16* G = (s < 2) ? A : Bt;
    const size_t gb = ((s < 2) ? Abase : Bbase) + (size_t)((s & 1) * 128) * FFN_ + T1 * 64;
    bf16* L = (bf16*)lds + c * 32768 + ((s < 2) ? 0 : 16384) + (s & 1) * 8192 + wbase;
#pragma unroll
    for (int i = 0; i < 2; ++i) {
      const int row = i * 64 + qrow0;          // row&7 == qrow0&7 (i*64 ≡ 0 mod 8)
      gl_lds16(G + gb + (size_t)row * FFN_ + qc8 * 8, L + i * 4096);
    }
  };
  auto ldA = [&](int c, int m, int kk) -> bf16x8 {   // read swizzle: slot ^= row&7
    const int row = wm * 128 + m * 16 + fr;
    const int off = (row * 64 + kk * 32 + fk) ^ ((row & 7) << 3);
    return *(const bf16x8*)((const bf16*)lds + c * 32768 + off);
  };
  auto ldB = [&](int c, int n, int kk) -> bf16x8 {
    const int row = wn * 64 + n * 16 + fr;
    const int off = (row * 64 + kk * 32 + fk) ^ ((row & 7) << 3);
    return *(const bf16x8*)((const bf16*)lds + c * 32768 + 16384 + off);
  };

  // prologue: tile0 fully + s0 of tile1; wait tile0 (leave 2 in flight)
  stage(0, 0); stage(1, 0); stage(2, 0); stage(3, 0);
  stage(0, 1);
  VM2();
  BAR();

#pragma unroll 2
  for (int T = 0; T < NT_; ++T) {
    const int c = T & 1;
    bf16x8 a1[4][2], a2[4][2], b[4][2];

    // ---- phase 1: reads Q0(12) + Q1's b(4); stage s1(T+1); MFMA Q0 ----
#pragma unroll
    for (int m = 0; m < 4; ++m) { a1[m][0] = ldA(c, m, 0); a1[m][1] = ldA(c, m, 1); }
#pragma unroll
    for (int n = 0; n < 2; ++n) { b[n][0] = ldB(c, n, 0); b[n][1] = ldB(c, n, 1); }
#pragma unroll
    for (int n = 2; n < 4; ++n) { b[n][0] = ldB(c, n, 0); b[n][1] = ldB(c, n, 1); }
    if (T + 1 < NT_) stage(1, T + 1);
    BAR();
    __builtin_amdgcn_s_setprio(1);
#pragma unroll
    for (int m = 0; m < 4; ++m)
#pragma unroll
      for (int n = 0; n < 2; ++n) {
        acc[m][n] = MFMA(a1[m][0], b[n][0], acc[m][n]);
        acc[m][n] = MFMA(a1[m][1], b[n][1], acc[m][n]);
      }
    __builtin_amdgcn_s_setprio(0);
    BAR();

    // ---- phase 2: reads Q2/Q3's a2(8); stage s2(T+1); MFMA Q1 ----
#pragma unroll
    for (int m = 0; m < 4; ++m) { a2[m][0] = ldA(c, m + 4, 0); a2[m][1] = ldA(c, m + 4, 1); }
    if (T + 1 < NT_) stage(2, T + 1);
    BAR();
    __builtin_amdgcn_s_setprio(1);
#pragma unroll
    for (int m = 0; m < 4; ++m)
#pragma unroll
      for (int n = 2; n < 4; ++n) {
        acc[m][n] = MFMA(a1[m][0], b[n][0], acc[m][n]);
        acc[m][n] = MFMA(a1[m][1], b[n][1], acc[m][n]);
      }
    __builtin_amdgcn_s_setprio(0);
    BAR();

    // ---- phase 3: stage s3(T+1); MFMA Q2 ----
    if (T + 1 < NT_) stage(3, T + 1);
    BAR();
    __builtin_amdgcn_s_setprio(1);
#pragma unroll
    for (int m = 0; m < 4; ++m)
#pragma unroll
      for (int n = 0; n < 2; ++n) {
        acc[m + 4][n] = MFMA(a2[m][0], b[n][0], acc[m + 4][n]);
        acc[m + 4][n] = MFMA(a2[m][1], b[n][1], acc[m + 4][n]);
      }
    __builtin_amdgcn_s_setprio(0);
    BAR();

    // ---- phase 4: stage s0(T+2); MFMA Q3; counted vmcnt ----
    if (T + 2 < NT_) stage(0, T + 2);
    BAR();
    __builtin_amdgcn_s_setprio(1);
#pragma unroll
    for (int m = 0; m < 4; ++m)
#pragma unroll
      for (int n = 2; n < 4; ++n) {
        acc[m + 4][n] = MFMA(a2[m][0], b[n][0], acc[m + 4][n]);
        acc[m + 4][n] = MFMA(a2[m][1], b[n][1], acc[m + 4][n]);
      }
    __builtin_amdgcn_s_setprio(0);
    if (T < NT_ - 2) { VM2(); } else { VM0(); }
    BAR();
  }

  // epilogue: C/D layout col=lane&15, row=(lane>>4)*4+j (m89/m91)
  const int orow = (lane >> 4) * 4, ocol = lane & 15;
  const int rbase = row0 + mi * 256 + wm * 128;
  const int cbase = ni * 256 + wn * 64;
#pragma unroll
  for (int m = 0; m < 8; ++m)
#pragma unroll
    for (int n = 0; n < 4; ++n)
#pragma unroll
      for (int j = 0; j < 4; ++j)
        C[(size_t)(rbase + m * 16 + orow + j) * NOUT + (cbase + n * 16 + ocol)] =
            acc[m][n][j];
}

// ============================================================
extern "C" void kernel_launch(void* const* d_in, const int* in_sizes, int n_in,
                              void* d_out, int out_size, void* d_ws, size_t ws_size,
                              hipStream_t stream) {
  const float* x    = (const float*)d_in[0];
  const float* Wenc = (const float*)d_in[1];
  const float* Wdec = (const float*)d_in[2];
  const float* Wout = (const float*)d_in[3];
  float* out = (float*)d_out;

  char* ws = (char*)d_ws;
  bf16*  Wb = (bf16*)ws;                          // 8 MiB
  float* z  = (float*)(ws + 8388608);             // 1 MiB
  bf16*  h  = (bf16*)(ws + 8388608 + 1048576);    // up to 256 MiB

  const size_t head = 8388608 + 1048576;
  const size_t avail = ws_size > head ? ws_size - head : 0;
  int nch = 1;
  while (nch < 128 && (size_t)(MROWS / nch) * FFN_ * 2 > avail) nch <<= 1;
  const int chunk = MROWS / nch;   // multiple of 256

  k_wcvt<<<4096, 256, 0, stream>>>(Wout, Wb);
  k_encode<<<2048, 256, 0, stream>>>(x, Wenc, z);
  for (int c = 0; c < nch; ++c) {
    const int row0 = c * chunk;
    dim3 hg(chunk / 64, 2);
    k_hgen<<<hg, 256, 0, stream>>>(z, Wdec, h, row0);
    k_gemm8<<<(chunk / 256) * 4, 512, 0, stream>>>(h, Wb, out, row0);
  }
}

// Round 7
// 372.267 us; speedup vs baseline: 1.3237x; 1.3237x over previous
//
#include <hip/hip_runtime.h>
#include <hip/hip_bf16.h>
#include <stdint.h>

typedef __bf16 bf16;
typedef bf16 bf16x8 __attribute__((ext_vector_type(8)));
typedef bf16 bf16x4 __attribute__((ext_vector_type(4)));
typedef float f32x4 __attribute__((ext_vector_type(4)));

#define NQ_    8
#define EMBED_ 1024
#define FFN_   4096
#define MROWS  32768   // B*S = 8*4096
#define NOUT   1024    // EMBED
#define NT_    (FFN_ / 64)   // 64 K-tiles of BK=64

// ---- async global->LDS, 16B per lane, wave-uniform LDS base ----
__device__ __forceinline__ void gl_lds16(const bf16* g, bf16* l) {
  __builtin_amdgcn_global_load_lds(
      (__attribute__((address_space(1))) void*)(const_cast<bf16*>(g)),
      (__attribute__((address_space(3))) void*)l, 16, 0, 0);
}

#define BAR()   __builtin_amdgcn_s_barrier()
#define LGKM0() asm volatile("s_waitcnt lgkmcnt(0)" ::: "memory")
#define LGKM8() asm volatile("s_waitcnt lgkmcnt(8)" ::: "memory")
#define VM2()   asm volatile("s_waitcnt vmcnt(2)" ::: "memory")
#define VM0()   asm volatile("s_waitcnt vmcnt(0)" ::: "memory")
#define MFMA(a, b, c) __builtin_amdgcn_mfma_f32_16x16x32_bf16((a), (b), (c), 0, 0, 0)

// ============================================================
// Kernel 1: W_out f32 -> bf16
// ============================================================
__global__ __launch_bounds__(256) void k_wcvt(const float* __restrict__ w,
                                              bf16* __restrict__ wb) {
  const int i = (blockIdx.x * 256 + threadIdx.x) * 4;
  const float4 v = *(const float4*)(w + i);
  bf16x4 o;
  o[0] = (bf16)v.x; o[1] = (bf16)v.y; o[2] = (bf16)v.z; o[3] = (bf16)v.w;
  *(bf16x4*)(wb + i) = o;
}

// ============================================================
// Kernel 2: theta = x @ W_enc^T ; z = analytic circuit expvals
//   z_0 = prod_{w=1..7} cos(theta_w); z_k = prod_{w=0..k} cos(theta_w)
// ============================================================
__global__ __launch_bounds__(256) void k_encode(const float* __restrict__ x,
                                                const float* __restrict__ Wenc,
                                                float* __restrict__ z) {
  const int t = threadIdx.x;
  const int wave = t >> 6, lane = t & 63;
  const int r0 = blockIdx.x * 16;

  float4 we[8];
#pragma unroll
  for (int q = 0; q < 8; ++q)
    we[q] = *(const float4*)(Wenc + q * EMBED_ + t * 4);

  __shared__ float red[16][4][8];
  __shared__ float cb[16][8];

  for (int rr = 0; rr < 16; ++rr) {
    const float4 xv = *(const float4*)(x + (size_t)(r0 + rr) * EMBED_ + t * 4);
#pragma unroll
    for (int q = 0; q < 8; ++q) {
      float v = xv.x * we[q].x + xv.y * we[q].y + xv.z * we[q].z + xv.w * we[q].w;
#pragma unroll
      for (int off = 32; off > 0; off >>= 1) v += __shfl_xor(v, off, 64);
      if (lane == 0) red[rr][wave][q] = v;
    }
  }
  __syncthreads();
  if (t < 128) {
    const int rr = t >> 3, q = t & 7;
    const float th = red[rr][0][q] + red[rr][1][q] + red[rr][2][q] + red[rr][3][q];
    cb[rr][q] = cosf(th);
  }
  __syncthreads();
  if (t < 16) {
    float c[8];
#pragma unroll
    for (int q = 0; q < 8; ++q) c[q] = cb[t][q];
    float zz[8];
    zz[0] = c[1] * c[2] * c[3] * c[4] * c[5] * c[6] * c[7];
    float p = c[0];
#pragma unroll
    for (int k = 1; k < 8; ++k) { p *= c[k]; zz[k] = p; }
    float4* zp = (float4*)(z + (size_t)(r0 + t) * 8);
    zp[0] = make_float4(zz[0], zz[1], zz[2], zz[3]);
    zp[1] = make_float4(zz[4], zz[5], zz[6], zz[7]);
  }
}

// ============================================================
// Kernel 3: h = relu(z @ W_dec^T) -> bf16 [chunk_rows][4096]
// ============================================================
__global__ __launch_bounds__(256) void k_hgen(const float* __restrict__ z,
                                              const float* __restrict__ Wdec,
                                              bf16* __restrict__ h,
                                              int row0) {
  const int t = threadIdx.x;
  const int f0 = blockIdx.y * 2048 + t * 8;
  const int g0 = row0 + blockIdx.x * 64;
  const int l0 = blockIdx.x * 64;

  float4 wd[16];
#pragma unroll
  for (int i = 0; i < 16; ++i)
    wd[i] = *(const float4*)(Wdec + (size_t)f0 * 8 + i * 4);

  for (int rr = 0; rr < 64; ++rr) {
    const float4* zp = (const float4*)(z + (size_t)(g0 + rr) * 8);
    const float4 z0 = zp[0], z1 = zp[1];
    bf16x8 o;
#pragma unroll
    for (int j = 0; j < 8; ++j) {
      const float4 a = wd[j * 2], b = wd[j * 2 + 1];
      float s = a.x * z0.x + a.y * z0.y + a.z * z0.z + a.w * z0.w +
                b.x * z1.x + b.y * z1.y + b.z * z1.z + b.w * z1.w;
      o[j] = (bf16)fmaxf(s, 0.0f);
    }
    *(bf16x8*)(h + (size_t)(l0 + rr) * FFN_ + f0) = o;
  }
}

// ============================================================
// Kernel 4: out = h @ W_out^T — r5 schedule (253us/47%) with
// flattened addressing:
//  - ds_read addrs: 4 per-lane base regs (a0, a1=a0^32, b0, b1),
//    m walks via offset: imm.  (row*64+kk*32+fk)^((row&7)<<3)
//    == row*64 + ((kk*32+fk)^swz); row&7==fr&7; XOR hits bit5 so
//    kk toggles via ^32 (verified numerically vs r5 formula).
//  - staging: 8 persistent global pointers advanced +=64/tile;
//    ahead*64 folds to an immediate.
// r6 lesson: NO cross-phase operand prefetch (spills at acc=128).
// ============================================================
__global__ __launch_bounds__(512, 2) void k_gemm8(const bf16* __restrict__ A,
                                                  const bf16* __restrict__ Bt,
                                                  float* __restrict__ C,
                                                  int row0) {
  __shared__ bf16 lds[65536];  // 128 KiB: buf c at c*32768 elems = [A 16384 | B 16384]

  // bijective XCD swizzle (m204)
  const int nwg = (int)gridDim.x, orig = (int)blockIdx.x;
  const int qd = nwg >> 3, rm = nwg & 7;
  const int xcd = orig & 7;
  const int bid = (xcd < rm ? xcd * (qd + 1) : rm * (qd + 1) + (xcd - rm) * qd) + (orig >> 3);
  const int mi = bid >> 2, ni = bid & 3;

  const int t = threadIdx.x;
  const int wave = t >> 6, lane = t & 63;
  const int wm = wave >> 2, wn = wave & 3;

  // staging geometry: thread t covers row qrow0 (+64k), pre-swizzled slot qc8
  const int qrow0 = t >> 3;
  const int qc8 = (t & 7) ^ (qrow0 & 7);
  const int wbase = wave * 512;            // wave-uniform LDS base (1024 B/wave)

  // 8 persistent global pointers (advanced += 64 elems per K-tile)
  const bf16* gA = A + (size_t)(mi * 256 + qrow0) * FFN_ + qc8 * 8;
  const bf16* gB = Bt + (size_t)(ni * 256 + qrow0) * FFN_ + qc8 * 8;
  const bf16* pA0 = gA;
  const bf16* pA1 = gA + (size_t)64 * FFN_;
  const bf16* pA2 = gA + (size_t)128 * FFN_;
  const bf16* pA3 = gA + (size_t)192 * FFN_;
  const bf16* pB0 = gB;
  const bf16* pB1 = gB + (size_t)64 * FFN_;
  const bf16* pB2 = gB + (size_t)128 * FFN_;
  const bf16* pB3 = gB + (size_t)192 * FFN_;

  // STAGE(sub-tile): 2x gl_lds, dest linear + wave-uniform base
#define STAGE(p0, p1, roff, ahead, cc)                                          \
  do {                                                                          \
    gl_lds16((p0) + (ahead) * 64, (bf16*)lds + (cc) * 32768 + (roff) + wbase);  \
    gl_lds16((p1) + (ahead) * 64,                                               \
             (bf16*)lds + (cc) * 32768 + (roff) + 4096 + wbase);                \
  } while (0)

  // flattened per-lane ds_read bases (elems)
  const int fr = lane & 15, fk = (lane >> 4) * 8;
  const int swz = (fr & 7) << 3;
  const int a0 = (wm * 128 + fr) * 64 + (fk ^ swz);
  const int a1 = a0 ^ 32;
  const int b0 = 16384 + (wn * 64 + fr) * 64 + (fk ^ swz);
  const int b1 = b0 ^ 32;

  auto ldA = [&](int c, int m, int kk) -> bf16x8 {
    return *(const bf16x8*)((const bf16*)lds + c * 32768 + (kk ? a1 : a0) + m * 1024);
  };
  auto ldB = [&](int c, int n, int kk) -> bf16x8 {
    return *(const bf16x8*)((const bf16*)lds + c * 32768 + (kk ? b1 : b0) + n * 1024);
  };

  f32x4 acc[8][4] = {};

  // prologue: tile0 fully (c=0) + s0 of tile1 (c=1); leave 2 in flight
  STAGE(pA0, pA1, 0, 0, 0);
  STAGE(pA2, pA3, 8192, 0, 0);
  STAGE(pB0, pB1, 16384, 0, 0);
  STAGE(pB2, pB3, 24576, 0, 0);
  STAGE(pA0, pA1, 0, 1, 1);
  VM2();
  BAR();

#pragma unroll 2
  for (int T = 0; T < NT_; ++T) {
    const int c = T & 1, cn = c ^ 1;
    bf16x8 a1r[4][2], a2r[4][2], br[4][2];

    // ---- phase 1: reads a1(8)+b01(4); stage s1(T+1); MFMA Q0 ----
#pragma unroll
    for (int m = 0; m < 4; ++m) { a1r[m][0] = ldA(c, m, 0); a1r[m][1] = ldA(c, m, 1); }
#pragma unroll
    for (int n = 0; n < 2; ++n) { br[n][0] = ldB(c, n, 0); br[n][1] = ldB(c, n, 1); }
    if (T + 1 < NT_) STAGE(pA2, pA3, 8192, 1, cn);
    LGKM8();
    BAR(); LGKM0();
    __builtin_amdgcn_s_setprio(1);
#pragma unroll
    for (int m = 0; m < 4; ++m)
#pragma unroll
      for (int n = 0; n < 2; ++n) {
        acc[m][n] = MFMA(a1r[m][0], br[n][0], acc[m][n]);
        acc[m][n] = MFMA(a1r[m][1], br[n][1], acc[m][n]);
      }
    __builtin_amdgcn_s_setprio(0);
    BAR();

    // ---- phase 2: reads b23(4); stage s2(T+1); MFMA Q1 ----
#pragma unroll
    for (int n = 2; n < 4; ++n) { br[n][0] = ldB(c, n, 0); br[n][1] = ldB(c, n, 1); }
    if (T + 1 < NT_) STAGE(pB0, pB1, 16384, 1, cn);
    BAR(); LGKM0();
    __builtin_amdgcn_s_setprio(1);
#pragma unroll
    for (int m = 0; m < 4; ++m)
#pragma unroll
      for (int n = 2; n < 4; ++n) {
        acc[m][n] = MFMA(a1r[m][0], br[n][0], acc[m][n]);
        acc[m][n] = MFMA(a1r[m][1], br[n][1], acc[m][n]);
      }
    __builtin_amdgcn_s_setprio(0);
    BAR();

    // ---- phase 3: reads a2(8); stage s3(T+1); MFMA Q2 ----
#pragma unroll
    for (int m = 0; m < 4; ++m) { a2r[m][0] = ldA(c, m + 4, 0); a2r[m][1] = ldA(c, m + 4, 1); }
    if (T + 1 < NT_) STAGE(pB2, pB3, 24576, 1, cn);
    BAR(); LGKM0();
    __builtin_amdgcn_s_setprio(1);
#pragma unroll
    for (int m = 0; m < 4; ++m)
#pragma unroll
      for (int n = 0; n < 2; ++n) {
        acc[m + 4][n] = MFMA(a2r[m][0], br[n][0], acc[m + 4][n]);
        acc[m + 4][n] = MFMA(a2r[m][1], br[n][1], acc[m + 4][n]);
      }
    __builtin_amdgcn_s_setprio(0);
    BAR();

    // ---- phase 4: stage s0(T+2)->c; MFMA Q3; counted vmcnt ----
    if (T + 2 < NT_) STAGE(pA0, pA1, 0, 2, c);
    BAR();
    __builtin_amdgcn_s_setprio(1);
#pragma unroll
    for (int m = 0; m < 4; ++m)
#pragma unroll
      for (int n = 2; n < 4; ++n) {
        acc[m + 4][n] = MFMA(a2r[m][0], br[n][0], acc[m + 4][n]);
        acc[m + 4][n] = MFMA(a2r[m][1], br[n][1], acc[m + 4][n]);
      }
    __builtin_amdgcn_s_setprio(0);
    if (T < NT_ - 2) { VM2(); } else { VM0(); }
    BAR();

    pA0 += 64; pA1 += 64; pA2 += 64; pA3 += 64;
    pB0 += 64; pB1 += 64; pB2 += 64; pB3 += 64;
  }
#undef STAGE

  // epilogue: C/D layout col=lane&15, row=(lane>>4)*4+j (m89/m91)
  const int orow = (lane >> 4) * 4, ocol = lane & 15;
  const int rbase = row0 + mi * 256 + wm * 128;
  const int cbase = ni * 256 + wn * 64;
#pragma unroll
  for (int m = 0; m < 8; ++m)
#pragma unroll
    for (int n = 0; n < 4; ++n)
#pragma unroll
      for (int j = 0; j < 4; ++j)
        C[(size_t)(rbase + m * 16 + orow + j) * NOUT + (cbase + n * 16 + ocol)] =
            acc[m][n][j];
}

// ============================================================
extern "C" void kernel_launch(void* const* d_in, const int* in_sizes, int n_in,
                              void* d_out, int out_size, void* d_ws, size_t ws_size,
                              hipStream_t stream) {
  const float* x    = (const float*)d_in[0];
  const float* Wenc = (const float*)d_in[1];
  const float* Wdec = (const float*)d_in[2];
  const float* Wout = (const float*)d_in[3];
  float* out = (float*)d_out;

  char* ws = (char*)d_ws;
  bf16*  Wb = (bf16*)ws;                          // 8 MiB
  float* z  = (float*)(ws + 8388608);             // 1 MiB
  bf16*  h  = (bf16*)(ws + 8388608 + 1048576);    // up to 256 MiB

  const size_t head = 8388608 + 1048576;
  const size_t avail = ws_size > head ? ws_size - head : 0;
  int nch = 1;
  while (nch < 128 && (size_t)(MROWS / nch) * FFN_ * 2 > avail) nch <<= 1;
  const int chunk = MROWS / nch;   // multiple of 256

  k_wcvt<<<4096, 256, 0, stream>>>(Wout, Wb);
  k_encode<<<2048, 256, 0, stream>>>(x, Wenc, z);
  for (int c = 0; c < nch; ++c) {
    const int row0 = c * chunk;
    dim3 hg(chunk / 64, 2);
    k_hgen<<<hg, 256, 0, stream>>>(z, Wdec, h, row0);
    k_gemm8<<<(chunk / 256) * 4, 512, 0, stream>>>(h, Wb, out, row0);
  }
}

// Round 8
// 365.293 us; speedup vs baseline: 1.3490x; 1.0191x over previous
//
#include <hip/hip_runtime.h>
#include <hip/hip_bf16.h>
#include <stdint.h>

typedef __bf16 bf16;
typedef bf16 bf16x8 __attribute__((ext_vector_type(8)));
typedef bf16 bf16x4 __attribute__((ext_vector_type(4)));
typedef float f32x4 __attribute__((ext_vector_type(4)));

#define NQ_    8
#define EMBED_ 1024
#define FFN_   4096
#define MROWS  32768   // B*S = 8*4096
#define NOUT   1024    // EMBED
#define NT_    (FFN_ / 64)   // 64 K-tiles of BK=64

// ---- async global->LDS, 16B per lane, wave-uniform LDS base ----
__device__ __forceinline__ void gl_lds16(const bf16* g, bf16* l) {
  __builtin_amdgcn_global_load_lds(
      (__attribute__((address_space(1))) void*)(const_cast<bf16*>(g)),
      (__attribute__((address_space(3))) void*)l, 16, 0, 0);
}

#define BAR()   __builtin_amdgcn_s_barrier()
#define LGKM0() asm volatile("s_waitcnt lgkmcnt(0)" ::: "memory")
#define LGKM8() asm volatile("s_waitcnt lgkmcnt(8)" ::: "memory")
#define VM4()   asm volatile("s_waitcnt vmcnt(4)" ::: "memory")
#define VM0()   asm volatile("s_waitcnt vmcnt(0)" ::: "memory")
#define MFMA(a, b, c) __builtin_amdgcn_mfma_f32_16x16x32_bf16((a), (b), (c), 0, 0, 0)

// ============================================================
// Kernel 1: W_out f32 -> bf16
// ============================================================
__global__ __launch_bounds__(256) void k_wcvt(const float* __restrict__ w,
                                              bf16* __restrict__ wb) {
  const int i = (blockIdx.x * 256 + threadIdx.x) * 4;
  const float4 v = *(const float4*)(w + i);
  bf16x4 o;
  o[0] = (bf16)v.x; o[1] = (bf16)v.y; o[2] = (bf16)v.z; o[3] = (bf16)v.w;
  *(bf16x4*)(wb + i) = o;
}

// ============================================================
// Kernel 2: theta = x @ W_enc^T ; z = analytic circuit expvals
//   z_0 = prod_{w=1..7} cos(theta_w); z_k = prod_{w=0..k} cos(theta_w)
// ============================================================
__global__ __launch_bounds__(256) void k_encode(const float* __restrict__ x,
                                                const float* __restrict__ Wenc,
                                                float* __restrict__ z) {
  const int t = threadIdx.x;
  const int wave = t >> 6, lane = t & 63;
  const int r0 = blockIdx.x * 16;

  float4 we[8];
#pragma unroll
  for (int q = 0; q < 8; ++q)
    we[q] = *(const float4*)(Wenc + q * EMBED_ + t * 4);

  __shared__ float red[16][4][8];
  __shared__ float cb[16][8];

  for (int rr = 0; rr < 16; ++rr) {
    const float4 xv = *(const float4*)(x + (size_t)(r0 + rr) * EMBED_ + t * 4);
#pragma unroll
    for (int q = 0; q < 8; ++q) {
      float v = xv.x * we[q].x + xv.y * we[q].y + xv.z * we[q].z + xv.w * we[q].w;
#pragma unroll
      for (int off = 32; off > 0; off >>= 1) v += __shfl_xor(v, off, 64);
      if (lane == 0) red[rr][wave][q] = v;
    }
  }
  __syncthreads();
  if (t < 128) {
    const int rr = t >> 3, q = t & 7;
    const float th = red[rr][0][q] + red[rr][1][q] + red[rr][2][q] + red[rr][3][q];
    cb[rr][q] = cosf(th);
  }
  __syncthreads();
  if (t < 16) {
    float c[8];
#pragma unroll
    for (int q = 0; q < 8; ++q) c[q] = cb[t][q];
    float zz[8];
    zz[0] = c[1] * c[2] * c[3] * c[4] * c[5] * c[6] * c[7];
    float p = c[0];
#pragma unroll
    for (int k = 1; k < 8; ++k) { p *= c[k]; zz[k] = p; }
    float4* zp = (float4*)(z + (size_t)(r0 + t) * 8);
    zp[0] = make_float4(zz[0], zz[1], zz[2], zz[3]);
    zp[1] = make_float4(zz[4], zz[5], zz[6], zz[7]);
  }
}

// ============================================================
// Kernel 3: h = relu(z @ W_dec^T) -> bf16 [chunk_rows][4096]
// ============================================================
__global__ __launch_bounds__(256) void k_hgen(const float* __restrict__ z,
                                              const float* __restrict__ Wdec,
                                              bf16* __restrict__ h,
                                              int row0) {
  const int t = threadIdx.x;
  const int f0 = blockIdx.y * 2048 + t * 8;
  const int g0 = row0 + blockIdx.x * 64;
  const int l0 = blockIdx.x * 64;

  float4 wd[16];
#pragma unroll
  for (int i = 0; i < 16; ++i)
    wd[i] = *(const float4*)(Wdec + (size_t)f0 * 8 + i * 4);

  for (int rr = 0; rr < 64; ++rr) {
    const float4* zp = (const float4*)(z + (size_t)(g0 + rr) * 8);
    const float4 z0 = zp[0], z1 = zp[1];
    bf16x8 o;
#pragma unroll
    for (int j = 0; j < 8; ++j) {
      const float4 a = wd[j * 2], b = wd[j * 2 + 1];
      float s = a.x * z0.x + a.y * z0.y + a.z * z0.z + a.w * z0.w +
                b.x * z1.x + b.y * z1.y + b.z * z1.z + b.w * z1.w;
      o[j] = (bf16)fmaxf(s, 0.0f);
    }
    *(bf16x8*)(h + (size_t)(l0 + rr) * FFN_ + f0) = o;
  }
}

// ============================================================
// Kernel 4: out = h @ W_out^T — r7 structure, DEEPENED STAGING:
//   ph1: reads a1(8)+b01(4) | stage s2(T+1)->c̄ | MFMA Q0
//   ph2: reads b23(4)       | stage s3(T+1)->c̄ | MFMA Q1
//   ph3: reads a2(8)        | stage s0(T+2)->c | MFMA Q2
//   ph4:                    | stage s1(T+2)->c | MFMA Q3, VM4
// Ledger: s0(T+2)->c rows0-127 safe at ph3 (A-reads of those rows
// retired at ph1 lgkm0+bar); s1(T+2) safe at ph4 (a2 retired ph3);
// B regions of c̄ consumed at ph2(T-?) before their restage. VM4 at
// ph4(T) drains exactly s0..s3(T+1); oldest required (s3) issued 2
// phases earlier (was 1 phase in r5/r7 -> suspected VM stall).
// Tail: VM0 for T>=NT-2. r6 lesson: no cross-phase operand prefetch.
// ============================================================
__global__ __launch_bounds__(512, 2) void k_gemm8(const bf16* __restrict__ A,
                                                  const bf16* __restrict__ Bt,
                                                  float* __restrict__ C,
                                                  int row0) {
  __shared__ bf16 lds[65536];  // 128 KiB: buf c at c*32768 elems = [A 16384 | B 16384]

  // bijective XCD swizzle (m204)
  const int nwg = (int)gridDim.x, orig = (int)blockIdx.x;
  const int qd = nwg >> 3, rm = nwg & 7;
  const int xcd = orig & 7;
  const int bid = (xcd < rm ? xcd * (qd + 1) : rm * (qd + 1) + (xcd - rm) * qd) + (orig >> 3);
  const int mi = bid >> 2, ni = bid & 3;

  const int t = threadIdx.x;
  const int wave = t >> 6, lane = t & 63;
  const int wm = wave >> 2, wn = wave & 3;

  // staging geometry: thread t covers row qrow0 (+64k), pre-swizzled slot qc8
  const int qrow0 = t >> 3;
  const int qc8 = (t & 7) ^ (qrow0 & 7);
  const int wbase = wave * 512;            // wave-uniform LDS base (1024 B/wave)

  // 8 persistent global pointers (advanced += 64 elems per K-tile)
  const bf16* gA = A + (size_t)(mi * 256 + qrow0) * FFN_ + qc8 * 8;
  const bf16* gB = Bt + (size_t)(ni * 256 + qrow0) * FFN_ + qc8 * 8;
  const bf16* pA0 = gA;
  const bf16* pA1 = gA + (size_t)64 * FFN_;
  const bf16* pA2 = gA + (size_t)128 * FFN_;
  const bf16* pA3 = gA + (size_t)192 * FFN_;
  const bf16* pB0 = gB;
  const bf16* pB1 = gB + (size_t)64 * FFN_;
  const bf16* pB2 = gB + (size_t)128 * FFN_;
  const bf16* pB3 = gB + (size_t)192 * FFN_;

  // STAGE(sub-tile): 2x gl_lds, dest linear + wave-uniform base
#define STAGE(p0, p1, roff, ahead, cc)                                          \
  do {                                                                          \
    gl_lds16((p0) + (ahead) * 64, (bf16*)lds + (cc) * 32768 + (roff) + wbase);  \
    gl_lds16((p1) + (ahead) * 64,                                               \
             (bf16*)lds + (cc) * 32768 + (roff) + 4096 + wbase);                \
  } while (0)

  // flattened per-lane ds_read bases (elems)
  const int fr = lane & 15, fk = (lane >> 4) * 8;
  const int swz = (fr & 7) << 3;
  const int a0 = (wm * 128 + fr) * 64 + (fk ^ swz);
  const int a1 = a0 ^ 32;
  const int b0 = 16384 + (wn * 64 + fr) * 64 + (fk ^ swz);
  const int b1 = b0 ^ 32;

  auto ldA = [&](int c, int m, int kk) -> bf16x8 {
    return *(const bf16x8*)((const bf16*)lds + c * 32768 + (kk ? a1 : a0) + m * 1024);
  };
  auto ldB = [&](int c, int n, int kk) -> bf16x8 {
    return *(const bf16x8*)((const bf16*)lds + c * 32768 + (kk ? b1 : b0) + n * 1024);
  };

  f32x4 acc[8][4] = {};

  // prologue: tile0 fully (c=0) + s0,s1 of tile1 (c=1); drain tile0, leave 4
  STAGE(pA0, pA1, 0, 0, 0);
  STAGE(pA2, pA3, 8192, 0, 0);
  STAGE(pB0, pB1, 16384, 0, 0);
  STAGE(pB2, pB3, 24576, 0, 0);
  STAGE(pA0, pA1, 0, 1, 1);
  STAGE(pA2, pA3, 8192, 1, 1);
  VM4();
  BAR();

#pragma unroll 2
  for (int T = 0; T < NT_; ++T) {
    const int c = T & 1, cn = c ^ 1;
    bf16x8 a1r[4][2], a2r[4][2], br[4][2];

    // ---- phase 1: reads a1(8)+b01(4); stage s2(T+1)->cn; MFMA Q0 ----
#pragma unroll
    for (int m = 0; m < 4; ++m) { a1r[m][0] = ldA(c, m, 0); a1r[m][1] = ldA(c, m, 1); }
#pragma unroll
    for (int n = 0; n < 2; ++n) { br[n][0] = ldB(c, n, 0); br[n][1] = ldB(c, n, 1); }
    if (T + 1 < NT_) STAGE(pB0, pB1, 16384, 1, cn);
    LGKM8();
    BAR(); LGKM0();
    __builtin_amdgcn_s_setprio(1);
#pragma unroll
    for (int m = 0; m < 4; ++m)
#pragma unroll
      for (int n = 0; n < 2; ++n) {
        acc[m][n] = MFMA(a1r[m][0], br[n][0], acc[m][n]);
        acc[m][n] = MFMA(a1r[m][1], br[n][1], acc[m][n]);
      }
    __builtin_amdgcn_s_setprio(0);
    BAR();

    // ---- phase 2: reads b23(4); stage s3(T+1)->cn; MFMA Q1 ----
#pragma unroll
    for (int n = 2; n < 4; ++n) { br[n][0] = ldB(c, n, 0); br[n][1] = ldB(c, n, 1); }
    if (T + 1 < NT_) STAGE(pB2, pB3, 24576, 1, cn);
    BAR(); LGKM0();
    __builtin_amdgcn_s_setprio(1);
#pragma unroll
    for (int m = 0; m < 4; ++m)
#pragma unroll
      for (int n = 2; n < 4; ++n) {
        acc[m][n] = MFMA(a1r[m][0], br[n][0], acc[m][n]);
        acc[m][n] = MFMA(a1r[m][1], br[n][1], acc[m][n]);
      }
    __builtin_amdgcn_s_setprio(0);
    BAR();

    // ---- phase 3: reads a2(8); stage s0(T+2)->c; MFMA Q2 ----
#pragma unroll
    for (int m = 0; m < 4; ++m) { a2r[m][0] = ldA(c, m + 4, 0); a2r[m][1] = ldA(c, m + 4, 1); }
    if (T + 2 < NT_) STAGE(pA0, pA1, 0, 2, c);
    BAR(); LGKM0();
    __builtin_amdgcn_s_setprio(1);
#pragma unroll
    for (int m = 0; m < 4; ++m)
#pragma unroll
      for (int n = 0; n < 2; ++n) {
        acc[m + 4][n] = MFMA(a2r[m][0], br[n][0], acc[m + 4][n]);
        acc[m + 4][n] = MFMA(a2r[m][1], br[n][1], acc[m + 4][n]);
      }
    __builtin_amdgcn_s_setprio(0);
    BAR();

    // ---- phase 4: stage s1(T+2)->c; MFMA Q3; counted vmcnt ----
    if (T + 2 < NT_) STAGE(pA2, pA3, 8192, 2, c);
    BAR();
    __builtin_amdgcn_s_setprio(1);
#pragma unroll
    for (int m = 0; m < 4; ++m)
#pragma unroll
      for (int n = 2; n < 4; ++n) {
        acc[m + 4][n] = MFMA(a2r[m][0], br[n][0], acc[m + 4][n]);
        acc[m + 4][n] = MFMA(a2r[m][1], br[n][1], acc[m + 4][n]);
      }
    __builtin_amdgcn_s_setprio(0);
    if (T < NT_ - 2) { VM4(); } else { VM0(); }
    BAR();

    pA0 += 64; pA1 += 64; pA2 += 64; pA3 += 64;
    pB0 += 64; pB1 += 64; pB2 += 64; pB3 += 64;
  }
#undef STAGE

  // epilogue: C/D layout col=lane&15, row=(lane>>4)*4+j (m89/m91)
  const int orow = (lane >> 4) * 4, ocol = lane & 15;
  const int rbase = row0 + mi * 256 + wm * 128;
  const int cbase = ni * 256 + wn * 64;
#pragma unroll
  for (int m = 0; m < 8; ++m)
#pragma unroll
    for (int n = 0; n < 4; ++n)
#pragma unroll
      for (int j = 0; j < 4; ++j)
        C[(size_t)(rbase + m * 16 + orow + j) * NOUT + (cbase + n * 16 + ocol)] =
            acc[m][n][j];
}

// ============================================================
extern "C" void kernel_launch(void* const* d_in, const int* in_sizes, int n_in,
                              void* d_out, int out_size, void* d_ws, size_t ws_size,
                              hipStream_t stream) {
  const float* x    = (const float*)d_in[0];
  const float* Wenc = (const float*)d_in[1];
  const float* Wdec = (const float*)d_in[2];
  const float* Wout = (const float*)d_in[3];
  float* out = (float*)d_out;

  char* ws = (char*)d_ws;
  bf16*  Wb = (bf16*)ws;                          // 8 MiB
  float* z  = (float*)(ws + 8388608);             // 1 MiB
  bf16*  h  = (bf16*)(ws + 8388608 + 1048576);    // up to 256 MiB

  const size_t head = 8388608 + 1048576;
  const size_t avail = ws_size > head ? ws_size - head : 0;
  int nch = 1;
  while (nch < 128 && (size_t)(MROWS / nch) * FFN_ * 2 > avail) nch <<= 1;
  const int chunk = MROWS / nch;   // multiple of 256

  k_wcvt<<<4096, 256, 0, stream>>>(Wout, Wb);
  k_encode<<<2048, 256, 0, stream>>>(x, Wenc, z);
  for (int c = 0; c < nch; ++c) {
    const int row0 = c * chunk;
    dim3 hg(chunk / 64, 2);
    k_hgen<<<hg, 256, 0, stream>>>(z, Wdec, h, row0);
    k_gemm8<<<(chunk / 256) * 4, 512, 0, stream>>>(h, Wb, out, row0);
  }
}